// Round 3
// baseline (645.153 us; speedup 1.0000x reference)
//
#include <hip/hip_runtime.h>

#define BB 4
#define LL 4096
#define DD 128
#define KW (LL / 32)   // 128 mask-words per row

typedef float f32x4 __attribute__((ext_vector_type(4)));
typedef short bf16x8 __attribute__((ext_vector_type(8)));
typedef unsigned short u16x8 __attribute__((ext_vector_type(8)));
typedef unsigned short u16x4 __attribute__((ext_vector_type(4)));
typedef int i32x4 __attribute__((ext_vector_type(4)));

__device__ __forceinline__ unsigned short f2bf(float f) {
  union { float f; unsigned u; } v; v.f = f;
  unsigned r = v.u + 0x7FFFu + ((v.u >> 16) & 1u);
  return (unsigned short)(r >> 16);
}

template <typename T>
__device__ __forceinline__ void nt_store(T* p, T v) {
  __builtin_nontemporal_store(v, p);
}

// ---- fused: row norms (fp32-exact) + bf16 conversion of Q,K ----
__global__ __launch_bounds__(256) void kNC(const float* __restrict__ Q,
                                           const float* __restrict__ K,
                                           unsigned short* __restrict__ Qb,
                                           unsigned short* __restrict__ Kb,
                                           float* __restrict__ qn,
                                           float* __restrict__ kn) {
  int tid = threadIdx.x;
  int row = blockIdx.x * 16 + (tid >> 4);  // 0..32767
  int part = tid & 15;
  const float* src; unsigned short* dst; float* nd; int r;
  if (row < BB * LL) { src = Q; dst = Qb; nd = qn; r = row; }
  else { src = K; dst = Kb; nd = kn; r = row - BB * LL; }
  const float* p = src + (size_t)r * DD + part * 8;
  f32x4 a = *(const f32x4*)p, b = *(const f32x4*)(p + 4);
  float s = a.x * a.x + a.y * a.y + a.z * a.z + a.w * a.w +
            b.x * b.x + b.y * b.y + b.z * b.z + b.w * b.w;
  s += __shfl_xor(s, 1); s += __shfl_xor(s, 2);
  s += __shfl_xor(s, 4); s += __shfl_xor(s, 8);
  u16x8 h;
  h[0] = f2bf(a.x); h[1] = f2bf(a.y); h[2] = f2bf(a.z); h[3] = f2bf(a.w);
  h[4] = f2bf(b.x); h[5] = f2bf(b.y); h[6] = f2bf(b.z); h[7] = f2bf(b.w);
  *(u16x8*)(dst + (size_t)r * DD + part * 8) = h;
  if (part == 0) nd[r] = s;
}

// ---- V transpose to bf16: VT[b][d][k] = bf16(V[b][k][d]) ----
__global__ __launch_bounds__(256) void kVT(const float* __restrict__ V,
                                           unsigned short* __restrict__ VT) {
  __shared__ unsigned short t[128][68];
  int bx = blockIdx.x;
  int kt = bx & 63, b = bx >> 6;
  int k0 = kt * 64;
  int tid = threadIdx.x;
  const float* Vb = V + ((size_t)b * LL + k0) * DD;
  #pragma unroll
  for (int i = 0; i < 8; ++i) {
    int flat = tid + i * 256;
    int row = flat >> 5, c4 = flat & 31;
    f32x4 v = *(const f32x4*)(Vb + row * DD + c4 * 4);
    #pragma unroll
    for (int j = 0; j < 4; ++j) t[c4 * 4 + j][row] = f2bf(v[j]);
  }
  __syncthreads();
  unsigned short* Ob = VT + (size_t)b * DD * LL + k0;
  #pragma unroll
  for (int i = 0; i < 8; ++i) {
    int flat = tid + i * 256;
    int d = flat >> 4, c = flat & 15;
    *(u16x4*)(Ob + (size_t)d * LL + c * 4) = *(const u16x4*)&t[d][c * 4];
  }
}

// ---- kernel A: dist2 + scores + mask-bit compression + row-sum-exp ----
// grid 1024: qb(128) x b(4) x ks(2). Block = 4 waves; block covers 32 q rows,
// wave w covers k = ks*2048 + t*128 + w*32 .. +32 (M-tile pair -> full 128B
// lines for mask reads and both stores). Mask stream 1-deep software-pipelined.
__global__ __launch_bounds__(256, 2) void kA3(
    const unsigned short* __restrict__ Qb, const unsigned short* __restrict__ Kb,
    const int* __restrict__ mask, const float* __restrict__ qn,
    const float* __restrict__ kn, float* __restrict__ scores,
    float* __restrict__ dist2, unsigned* __restrict__ mbits,
    float* __restrict__ l_part) {
  __shared__ float lds_l[4][32];
  int bx = blockIdx.x;
  int qb = bx & 127, b = (bx >> 7) & 3, ks = bx >> 9;
  int tid = threadIdx.x;
  int w = tid >> 6, lane = tid & 63, lr = lane >> 4, lc = lane & 15;
  int q0 = qb * 32;
  size_t bL = (size_t)b * LL;

  bf16x8 qf[2][4];
  float qn_r[2];
  size_t rowoff[2];
  #pragma unroll
  for (int qs = 0; qs < 2; ++qs) {
    int q = q0 + qs * 16 + lc;
    qn_r[qs] = qn[bL + q];
    rowoff[qs] = (bL + q) * (size_t)LL;
    const unsigned short* qp = Qb + (bL + q) * DD;
    #pragma unroll
    for (int c = 0; c < 4; ++c)
      qf[qs][c] = *(const bf16x8*)(qp + c * 32 + lr * 8);
  }

  float l_acc[2] = {0.f, 0.f};

  auto KBASE = [&](int t) { return ks * 2048 + t * 128 + w * 32; };

  auto LOADM = [&](i32x4 (&m_)[2][2], int t) {
    int kb = KBASE(t);
    #pragma unroll
    for (int qs = 0; qs < 2; ++qs)
      #pragma unroll
      for (int e = 0; e < 2; ++e)
        m_[qs][e] = *(const i32x4*)(mask + rowoff[qs] + kb + e * 16 + lr * 4);
  };

  auto COMPUTE = [&](i32x4 (&m_)[2][2], int t) {
    int kb = KBASE(t);
    bf16x8 af[2][4];
    #pragma unroll
    for (int e = 0; e < 2; ++e) {
      const unsigned short* kp = Kb + (bL + kb + e * 16 + lc) * DD;
      #pragma unroll
      for (int c = 0; c < 4; ++c)
        af[e][c] = *(const bf16x8*)(kp + c * 32 + lr * 8);
    }
    f32x4 kn4[2];
    #pragma unroll
    for (int e = 0; e < 2; ++e)
      kn4[e] = *(const f32x4*)(kn + bL + kb + e * 16 + lr * 4);
    #pragma unroll
    for (int qs = 0; qs < 2; ++qs) {
      unsigned ubits = 0;
      #pragma unroll
      for (int e = 0; e < 2; ++e) {
        f32x4 S = (f32x4){0.f, 0.f, 0.f, 0.f};
        #pragma unroll
        for (int c = 0; c < 4; ++c)
          S = __builtin_amdgcn_mfma_f32_16x16x32_bf16(af[e][c], qf[qs][c], S, 0, 0, 0);
        f32x4 d2, sv;
        float le = 0.f;
        #pragma unroll
        for (int r = 0; r < 4; ++r) {
          float d = qn_r[qs] + kn4[e][r] - 2.0f * S[r];
          d2[r] = d;
          float sc = d * (-1.0f / 256.0f);
          bool ms = (m_[qs][e][r] == 0);
          sv[r] = ms ? -__builtin_inff() : sc;
          le += ms ? 0.f : __expf(sc);
          ubits |= (ms ? 0u : 1u) << (e * 16 + lr * 4 + r);
        }
        size_t off = rowoff[qs] + kb + e * 16 + lr * 4;
        nt_store((f32x4*)(dist2 + off), d2);
        nt_store((f32x4*)(scores + off), sv);
        l_acc[qs] += le;
      }
      ubits |= __shfl_xor(ubits, 16);
      ubits |= __shfl_xor(ubits, 32);
      if (lr == 0)
        mbits[((size_t)b * KW + (kb >> 5)) * LL + q0 + qs * 16 + lc] = ubits;
    }
  };

  i32x4 mA[2][2], mB[2][2];
  LOADM(mA, 0);
  #pragma unroll
  for (int tt = 0; tt < 8; ++tt) {
    LOADM(mB, 2 * tt + 1);
    COMPUTE(mA, 2 * tt);
    LOADM(mA, (2 * tt + 2 < 16) ? 2 * tt + 2 : 15);  // t=15 dup is safe
    COMPUTE(mB, 2 * tt + 1);
  }

  #pragma unroll
  for (int qs = 0; qs < 2; ++qs) {
    float v = l_acc[qs];
    v += __shfl_xor(v, 16);
    v += __shfl_xor(v, 32);
    if (lane < 16) lds_l[w][qs * 16 + lane] = v;
  }
  __syncthreads();
  if (tid < 32) {
    float s = lds_l[0][tid] + lds_l[1][tid] + lds_l[2][tid] + lds_l[3][tid];
    l_part[(size_t)ks * (BB * LL) + bL + q0 + tid] = s;
  }
}

// ---- kernel B: recompute S from L2-resident bf16 Q/K, P=exp via mask bits,
// write attn, PV MFMA -> O_part. grid 1024: qb(64) x b(4) x ks(4).
// Wave w owns q rows qg..qg+16, k in [ks*1024, +1024). P goes C-frag -> LDS
// -> A-frag (same-wave DS order, no barrier).
__global__ __launch_bounds__(256, 2) void kB3(
    const unsigned short* __restrict__ Qb, const unsigned short* __restrict__ Kb,
    const unsigned short* __restrict__ VT, const unsigned* __restrict__ mbits,
    const float* __restrict__ qn, const float* __restrict__ kn,
    const float* __restrict__ l_part, float* __restrict__ attn,
    float* __restrict__ O_part) {
  __shared__ short plds[4][16][72];
  int bx = blockIdx.x;
  int qb = bx & 63, b = (bx >> 6) & 3, ks = bx >> 8;
  int tid = threadIdx.x;
  int w = tid >> 6, lane = tid & 63, lr = lane >> 4, lc = lane & 15;
  int qg = qb * 64 + w * 16;
  size_t bL = (size_t)b * LL;
  int q = qg + lc;

  bf16x8 qf2[4];
  {
    const unsigned short* qp = Qb + (bL + q) * DD;
    #pragma unroll
    for (int c = 0; c < 4; ++c)
      qf2[c] = *(const bf16x8*)(qp + c * 32 + lr * 8);
  }
  float qn_l = qn[bL + q];
  float rl = 1.0f / (l_part[bL + q] + l_part[(size_t)(BB * LL) + bL + q]);

  f32x4 o[8];
  #pragma unroll
  for (int f = 0; f < 8; ++f) o[f] = (f32x4){0.f, 0.f, 0.f, 0.f};

  const unsigned short* Kbb = Kb + bL * DD;
  const unsigned short* Vb = VT + (size_t)b * DD * LL;
  const unsigned* mb_base = mbits + (size_t)b * KW * LL + q;
  float* Ab = attn + (bL + q) * (size_t)LL;

  for (int t = 0; t < 16; ++t) {
    int k0 = ks * 1024 + t * 64;
    unsigned mw0 = mb_base[(size_t)((k0 >> 5) + 0) * LL];
    unsigned mw1 = mb_base[(size_t)((k0 >> 5) + 1) * LL];
    #pragma unroll
    for (int m = 0; m < 4; ++m) {
      int kk = k0 + m * 16;
      const unsigned short* kp = Kbb + (size_t)(kk + lc) * DD;
      f32x4 S = (f32x4){0.f, 0.f, 0.f, 0.f};
      #pragma unroll
      for (int c = 0; c < 4; ++c) {
        bf16x8 kaf = *(const bf16x8*)(kp + c * 32 + lr * 8);
        S = __builtin_amdgcn_mfma_f32_16x16x32_bf16(kaf, qf2[c], S, 0, 0, 0);
      }
      f32x4 kn4 = *(const f32x4*)(kn + bL + kk + lr * 4);
      unsigned mword = (m < 2) ? mw0 : mw1;
      int bs = (m & 1) * 16 + lr * 4;
      f32x4 av;
      u16x4 pb;
      #pragma unroll
      for (int r = 0; r < 4; ++r) {
        float d = qn_l + kn4[r] - 2.0f * S[r];
        float sc = d * (-1.0f / 256.0f);
        bool ms = ((mword >> (bs + r)) & 1u) == 0u;
        float pe = ms ? 0.f : __expf(sc);
        av[r] = pe * rl;
        pb[r] = f2bf(pe);
      }
      nt_store((f32x4*)(Ab + kk + lr * 4), av);
      *(u16x4*)&plds[w][lc][m * 16 + lr * 4] = pb;
    }
    bf16x8 pa[2];
    #pragma unroll
    for (int c = 0; c < 2; ++c)
      pa[c] = *(const bf16x8*)&plds[w][lc][c * 32 + lr * 8];
    #pragma unroll
    for (int f = 0; f < 8; ++f) {
      const unsigned short* vp = Vb + (size_t)(f * 16 + lc) * LL + k0 + lr * 8;
      #pragma unroll
      for (int c = 0; c < 2; ++c) {
        bf16x8 vb = *(const bf16x8*)(vp + c * 32);
        o[f] = __builtin_amdgcn_mfma_f32_16x16x32_bf16(pa[c], vb, o[f], 0, 0, 0);
      }
    }
  }

  float rlv[4];
  #pragma unroll
  for (int r = 0; r < 4; ++r) rlv[r] = __shfl(rl, lr * 4 + r);
  float* Ob = O_part + (size_t)ks * ((size_t)BB * LL * DD);
  #pragma unroll
  for (int f = 0; f < 8; ++f) {
    #pragma unroll
    for (int r = 0; r < 4; ++r)
      Ob[(bL + qg + lr * 4 + r) * DD + f * 16 + lc] = o[f][r] * rlv[r];
  }
}

// ---- reduce the four O partials into out ----
__global__ __launch_bounds__(256) void kR(const float* __restrict__ O_part,
                                          float* __restrict__ out) {
  size_t idx = (size_t)blockIdx.x * 256 + threadIdx.x;
  const size_t N4 = (size_t)BB * LL * DD / 4;
  const f32x4* a = (const f32x4*)O_part;
  f32x4 v = a[idx] + a[idx + N4] + a[idx + 2 * N4] + a[idx + 3 * N4];
  ((f32x4*)out)[idx] = v;
}

extern "C" void kernel_launch(void* const* d_in, const int* in_sizes, int n_in,
                              void* d_out, int out_size, void* d_ws, size_t ws_size,
                              hipStream_t stream) {
  const float* Q = (const float*)d_in[0];
  const float* K = (const float*)d_in[1];
  const float* V = (const float*)d_in[2];
  const int* mask = (const int*)d_in[3];

  float* out = (float*)d_out;                        // [4,4096,128]
  float* attn = out + (size_t)BB * LL * DD;          // [4,4096,4096]
  float* scores = attn + (size_t)BB * LL * LL;       // [4,4096,4096]
  float* dist2 = scores + (size_t)BB * LL * LL;      // [4,4096,4096]

  float* qn = (float*)d_ws;                                   // 16384 f
  float* kn = qn + BB * LL;                                   // 16384 f
  float* l_part = kn + BB * LL;                               // 2*16384 f
  unsigned short* Qbf = (unsigned short*)(l_part + 2 * BB * LL);   // 4 MB
  unsigned short* Kbf = Qbf + (size_t)BB * LL * DD;                // 4 MB
  unsigned short* VTb = Kbf + (size_t)BB * LL * DD;                // 4 MB
  unsigned* mbits = (unsigned*)(VTb + (size_t)BB * LL * DD);       // 8 MB
  float* O_part = (float*)(mbits + (size_t)BB * KW * LL);          // 4 x 8 MB

  hipLaunchKernelGGL(kNC, dim3(2048), dim3(256), 0, stream, Q, K, Qbf, Kbf, qn, kn);
  hipLaunchKernelGGL(kVT, dim3(256), dim3(256), 0, stream, V, VTb);
  hipLaunchKernelGGL(kA3, dim3(1024), dim3(256), 0, stream, Qbf, Kbf, mask, qn,
                     kn, scores, dist2, mbits, l_part);
  hipLaunchKernelGGL(kB3, dim3(1024), dim3(256), 0, stream, Qbf, Kbf, VTb,
                     mbits, qn, kn, l_part, attn, O_part);
  hipLaunchKernelGGL(kR, dim3(2048), dim3(256), 0, stream, O_part, out);
}

// Round 4
// 531.483 us; speedup vs baseline: 1.2139x; 1.2139x over previous
//
#include <hip/hip_runtime.h>

#define BB 4
#define LL 4096
#define DD 128

typedef float f32x4 __attribute__((ext_vector_type(4)));
typedef short bf16x8 __attribute__((ext_vector_type(8)));
typedef unsigned short u16x8 __attribute__((ext_vector_type(8)));
typedef unsigned short u16x4 __attribute__((ext_vector_type(4)));
typedef int i32x4 __attribute__((ext_vector_type(4)));

__device__ __forceinline__ unsigned short f2bf(float f) {
  union { float f; unsigned u; } v; v.f = f;
  unsigned r = v.u + 0x7FFFu + ((v.u >> 16) & 1u);
  return (unsigned short)(r >> 16);
}

// ---- fused: row norms (fp32-exact) + bf16 conversion of Q,K ----
__global__ __launch_bounds__(256) void kNC(const float* __restrict__ Q,
                                           const float* __restrict__ K,
                                           unsigned short* __restrict__ Qb,
                                           unsigned short* __restrict__ Kb,
                                           float* __restrict__ qn,
                                           float* __restrict__ kn) {
  int tid = threadIdx.x;
  int row = blockIdx.x * 16 + (tid >> 4);  // 0..32767
  int part = tid & 15;
  const float* src; unsigned short* dst; float* nd; int r;
  if (row < BB * LL) { src = Q; dst = Qb; nd = qn; r = row; }
  else { src = K; dst = Kb; nd = kn; r = row - BB * LL; }
  const float* p = src + (size_t)r * DD + part * 8;
  f32x4 a = *(const f32x4*)p, b = *(const f32x4*)(p + 4);
  float s = a.x * a.x + a.y * a.y + a.z * a.z + a.w * a.w +
            b.x * b.x + b.y * b.y + b.z * b.z + b.w * b.w;
  s += __shfl_xor(s, 1); s += __shfl_xor(s, 2);
  s += __shfl_xor(s, 4); s += __shfl_xor(s, 8);
  u16x8 h;
  h[0] = f2bf(a.x); h[1] = f2bf(a.y); h[2] = f2bf(a.z); h[3] = f2bf(a.w);
  h[4] = f2bf(b.x); h[5] = f2bf(b.y); h[6] = f2bf(b.z); h[7] = f2bf(b.w);
  *(u16x8*)(dst + (size_t)r * DD + part * 8) = h;
  if (part == 0) nd[r] = s;
}

// ---- V transpose to bf16: VT[b][d][k] = bf16(V[b][k][d]) ----
__global__ __launch_bounds__(256) void kVT(const float* __restrict__ V,
                                           unsigned short* __restrict__ VT) {
  __shared__ unsigned short t[128][68];
  int bx = blockIdx.x;
  int kt = bx & 63, b = bx >> 6;
  int k0 = kt * 64;
  int tid = threadIdx.x;
  const float* Vb = V + ((size_t)b * LL + k0) * DD;
  #pragma unroll
  for (int i = 0; i < 8; ++i) {
    int flat = tid + i * 256;
    int row = flat >> 5, c4 = flat & 31;
    f32x4 v = *(const f32x4*)(Vb + row * DD + c4 * 4);
    #pragma unroll
    for (int j = 0; j < 4; ++j) t[c4 * 4 + j][row] = f2bf(v[j]);
  }
  __syncthreads();
  unsigned short* Ob = VT + (size_t)b * DD * LL + k0;
  #pragma unroll
  for (int i = 0; i < 8; ++i) {
    int flat = tid + i * 256;
    int d = flat >> 4, c = flat & 15;
    *(u16x4*)(Ob + (size_t)d * LL + c * 4) = *(const u16x4*)&t[d][c * 4];
  }
}

// ---- kernel A4: dist2 + scores + row-sum-exp, full-line stores ----
// grid 1024: qb(64) x b(4) x ks(4). 4 waves/block; wave w owns q rows
// [qb*64+w*16, +16) over k in [ks*1024, +1024). Swapped MFMA (A=K,B=Q)
// gives lane 4 consecutive k; S-tile transposed via XOR-swizzled LDS so
// every mask-load / dist2-store / scores-store instruction covers 256B
// contiguous per row (full 128B lines). Row sums stay in registers.
__global__ __launch_bounds__(256, 2) void kA4(
    const unsigned short* __restrict__ Qb, const unsigned short* __restrict__ Kb,
    const int* __restrict__ mask, const float* __restrict__ qn,
    const float* __restrict__ kn, float* __restrict__ scores,
    float* __restrict__ dist2, float* __restrict__ l_part) {
  __shared__ float slds[4][16][64];  // [wave][q][k-chunk], XOR-swizzled in k
  int bx = blockIdx.x;
  int qb = bx & 63, b = (bx >> 6) & 3, ks = bx >> 8;
  int tid = threadIdx.x;
  int w = tid >> 6, lane = tid & 63, lr = lane >> 4, lc = lane & 15;
  int qg = qb * 64 + w * 16;
  size_t bL = (size_t)b * LL;

  // B-operand: Q fragments for row qg+lc (held for the whole kernel)
  bf16x8 qf[4];
  {
    const unsigned short* qp = Qb + (bL + qg + lc) * DD;
    #pragma unroll
    for (int c = 0; c < 4; ++c)
      qf[c] = *(const bf16x8*)(qp + c * 32 + lr * 8);
  }

  // store-phase identities: in sub-iter s, this lane handles
  // row = s*4 + lr (q = qg+row), k-segment lc (4 floats at k0+lc*4)
  float qn_s[4];
  size_t rowoff[4];
  #pragma unroll
  for (int s = 0; s < 4; ++s) {
    qn_s[s] = qn[bL + qg + s * 4 + lr];
    rowoff[s] = (bL + qg + s * 4 + lr) * (size_t)LL;
  }
  float l_acc[4] = {0.f, 0.f, 0.f, 0.f};

  auto MFMA_PHASE = [&](int t) {
    int k0 = ks * 1024 + t * 64;
    #pragma unroll
    for (int m = 0; m < 4; ++m) {
      const unsigned short* kp = Kb + (bL + k0 + m * 16 + lc) * DD;
      f32x4 S = (f32x4){0.f, 0.f, 0.f, 0.f};
      #pragma unroll
      for (int c = 0; c < 4; ++c) {
        bf16x8 af = *(const bf16x8*)(kp + c * 32 + lr * 8);
        S = __builtin_amdgcn_mfma_f32_16x16x32_bf16(af, qf[c], S, 0, 0, 0);
      }
      // C-frag: q=lc, k-chunk index (m*4+lr); physical chunk = chunk ^ q
      int swz = ((m * 4 + lr) ^ lc) & 15;
      *(f32x4*)&slds[w][lc][swz * 4] = S;
    }
  };

  auto LOADM = [&](i32x4 (&mr)[4], int t) {
    int k0 = ks * 1024 + t * 64;
    #pragma unroll
    for (int s = 0; s < 4; ++s)
      mr[s] = *(const i32x4*)(mask + rowoff[s] + k0 + lc * 4);
  };

  auto STORE_PHASE = [&](i32x4 (&mr)[4], int t) {
    int k0 = ks * 1024 + t * 64;
    f32x4 kn4 = *(const f32x4*)(kn + bL + k0 + lc * 4);
    #pragma unroll
    for (int s = 0; s < 4; ++s) {
      int row = s * 4 + lr;
      int swz = (lc ^ row) & 15;
      f32x4 S = *(const f32x4*)&slds[w][row][swz * 4];
      f32x4 d2, sv;
      float le = 0.f;
      #pragma unroll
      for (int r = 0; r < 4; ++r) {
        float d = qn_s[s] + kn4[r] - 2.0f * S[r];
        d2[r] = d;
        float sc = d * (-1.0f / 256.0f);
        bool ms = (mr[s][r] == 0);
        sv[r] = ms ? -__builtin_inff() : sc;
        le += ms ? 0.f : __expf(sc);
      }
      size_t off = rowoff[s] + k0 + lc * 4;
      *(f32x4*)(dist2 + off) = d2;
      *(f32x4*)(scores + off) = sv;
      le += __shfl_xor(le, 1); le += __shfl_xor(le, 2);
      le += __shfl_xor(le, 4); le += __shfl_xor(le, 8);
      l_acc[s] += le;
    }
  };

  i32x4 mA[4], mB[4];
  LOADM(mA, 0);
  #pragma unroll
  for (int tt = 0; tt < 8; ++tt) {
    MFMA_PHASE(2 * tt);
    LOADM(mB, 2 * tt + 1);
    STORE_PHASE(mA, 2 * tt);
    MFMA_PHASE(2 * tt + 1);
    LOADM(mA, (tt < 7) ? (2 * tt + 2) : 0);  // tail dup is harmless
    STORE_PHASE(mB, 2 * tt + 1);
  }

  // wave owns its rows' full k-range -> l_acc is the final partial sum
  if (lc == 0) {
    #pragma unroll
    for (int s = 0; s < 4; ++s)
      l_part[(size_t)ks * (BB * LL) + bL + qg + s * 4 + lr] = l_acc[s];
  }
}

// ---- kernel B: attn = exp(scores)/l, O_part = attn @ V (round-1 form) ----
// grid 512: qb(64) x b(4) x ks(2); block 256 (4 waves).
__global__ __launch_bounds__(256, 2) void kB(const float* __restrict__ scores,
    const float* __restrict__ l_part, const unsigned short* __restrict__ VT,
    float* __restrict__ attn, float* __restrict__ O_part) {
  __shared__ short p_lds[64 * 72];
  __shared__ short v_lds[128 * 72];
  __shared__ float rl_lds[64];
  int bx = blockIdx.x;
  int qb = bx & 63, b = (bx >> 6) & 3, ks = bx >> 8;
  int tid = threadIdx.x;
  int wq = tid >> 6, l = tid & 63, lr = l >> 4, lc = l & 15;
  int q0 = qb * 64;
  if (tid < 64) {
    float s = 0.f;
    #pragma unroll
    for (int sp = 0; sp < 4; ++sp)
      s += l_part[(size_t)sp * (BB * LL) + (size_t)b * LL + q0 + tid];
    rl_lds[tid] = 1.0f / s;
  }
  f32x4 o[8];
  #pragma unroll
  for (int f = 0; f < 8; ++f) o[f] = (f32x4){0.f, 0.f, 0.f, 0.f};
  const float* Sb = scores + (size_t)b * LL * LL + (size_t)q0 * LL;
  float* Ab = attn + (size_t)b * LL * LL + (size_t)q0 * LL;
  const unsigned short* Vb = VT + (size_t)b * DD * LL;
  __syncthreads();
  for (int t = 0; t < 32; ++t) {
    int k0 = ks * 2048 + t * 64;
    #pragma unroll
    for (int i = 0; i < 4; ++i) {
      int flat = tid + i * 256;
      int row = flat >> 4, c4 = flat & 15;
      size_t off = (size_t)row * LL + k0 + c4 * 4;
      f32x4 s4 = *(const f32x4*)(Sb + off);
      float r = rl_lds[row];
      f32x4 p4;
      p4.x = __expf(s4.x) * r; p4.y = __expf(s4.y) * r;
      p4.z = __expf(s4.z) * r; p4.w = __expf(s4.w) * r;
      *(f32x4*)(Ab + off) = p4;
      u16x4 h;
      h[0] = f2bf(p4.x); h[1] = f2bf(p4.y); h[2] = f2bf(p4.z); h[3] = f2bf(p4.w);
      *(u16x4*)&p_lds[row * 72 + c4 * 4] = h;
    }
    #pragma unroll
    for (int i = 0; i < 8; ++i) {
      int flat = tid + i * 256;
      int d = flat >> 4, c = flat & 15;
      *(u16x4*)&v_lds[d * 72 + c * 4] =
          *(const u16x4*)(Vb + (size_t)d * LL + k0 + c * 4);
    }
    __syncthreads();
    bf16x8 pa[2];
    #pragma unroll
    for (int c = 0; c < 2; ++c)
      pa[c] = *(bf16x8*)&p_lds[(wq * 16 + lc) * 72 + c * 32 + lr * 8];
    #pragma unroll
    for (int f = 0; f < 8; ++f) {
      #pragma unroll
      for (int c = 0; c < 2; ++c) {
        bf16x8 vb = *(bf16x8*)&v_lds[(f * 16 + lc) * 72 + c * 32 + lr * 8];
        o[f] = __builtin_amdgcn_mfma_f32_16x16x32_bf16(pa[c], vb, o[f], 0, 0, 0);
      }
    }
    __syncthreads();
  }
  float* Ob = O_part + (size_t)ks * ((size_t)BB * LL * DD);
  #pragma unroll
  for (int f = 0; f < 8; ++f) {
    #pragma unroll
    for (int r = 0; r < 4; ++r) {
      int row = q0 + wq * 16 + lr * 4 + r;
      Ob[((size_t)b * LL + row) * DD + f * 16 + lc] = o[f][r];
    }
  }
}

// ---- reduce the two O partials into out ----
__global__ __launch_bounds__(256) void kR(const float* __restrict__ O_part,
                                          float* __restrict__ out) {
  size_t idx = (size_t)blockIdx.x * 256 + threadIdx.x;
  const size_t N4 = (size_t)BB * LL * DD / 4;
  const f32x4* a = (const f32x4*)O_part;
  f32x4 v = a[idx] + a[idx + N4];
  ((f32x4*)out)[idx] = v;
}

extern "C" void kernel_launch(void* const* d_in, const int* in_sizes, int n_in,
                              void* d_out, int out_size, void* d_ws, size_t ws_size,
                              hipStream_t stream) {
  const float* Q = (const float*)d_in[0];
  const float* K = (const float*)d_in[1];
  const float* V = (const float*)d_in[2];
  const int* mask = (const int*)d_in[3];

  float* out = (float*)d_out;                        // [4,4096,128]
  float* attn = out + (size_t)BB * LL * DD;          // [4,4096,4096]
  float* scores = attn + (size_t)BB * LL * LL;       // [4,4096,4096]
  float* dist2 = scores + (size_t)BB * LL * LL;      // [4,4096,4096]

  float* qn = (float*)d_ws;                                   // 16384 f
  float* kn = qn + BB * LL;                                   // 16384 f
  float* l_part = kn + BB * LL;                               // 4*16384 f
  unsigned short* Qbf = (unsigned short*)(l_part + 4 * BB * LL);   // 4 MB
  unsigned short* Kbf = Qbf + (size_t)BB * LL * DD;                // 4 MB
  unsigned short* VTb = Kbf + (size_t)BB * LL * DD;                // 4 MB
  float* O_part = (float*)(VTb + (size_t)BB * LL * DD);            // 2 x 8 MB

  hipLaunchKernelGGL(kNC, dim3(2048), dim3(256), 0, stream, Q, K, Qbf, Kbf, qn, kn);
  hipLaunchKernelGGL(kVT, dim3(256), dim3(256), 0, stream, V, VTb);
  hipLaunchKernelGGL(kA4, dim3(1024), dim3(256), 0, stream, Qbf, Kbf, mask, qn,
                     kn, scores, dist2, l_part);
  hipLaunchKernelGGL(kB, dim3(512), dim3(256), 0, stream, scores, l_part, VTb,
                     attn, O_part);
  hipLaunchKernelGGL(kR, dim3(2048), dim3(256), 0, stream, O_part, out);
}

// Round 5
// 405.294 us; speedup vs baseline: 1.5918x; 1.3114x over previous
//
#include <hip/hip_runtime.h>

#define BB 4
#define LL 4096
#define DD 128

typedef float f32x4 __attribute__((ext_vector_type(4)));
typedef short bf16x8 __attribute__((ext_vector_type(8)));
typedef unsigned short u16x8 __attribute__((ext_vector_type(8)));
typedef unsigned short u16x4 __attribute__((ext_vector_type(4)));
typedef int i32x4 __attribute__((ext_vector_type(4)));

__device__ __forceinline__ unsigned short f2bf(float f) {
  union { float f; unsigned u; } v; v.f = f;
  unsigned r = v.u + 0x7FFFu + ((v.u >> 16) & 1u);
  return (unsigned short)(r >> 16);
}

// ---- fused: row norms (fp32-exact) + bf16 conversion of Q,K ----
__global__ __launch_bounds__(256) void kNC(const float* __restrict__ Q,
                                           const float* __restrict__ K,
                                           unsigned short* __restrict__ Qb,
                                           unsigned short* __restrict__ Kb,
                                           float* __restrict__ qn,
                                           float* __restrict__ kn) {
  int tid = threadIdx.x;
  int row = blockIdx.x * 16 + (tid >> 4);  // 0..32767
  int part = tid & 15;
  const float* src; unsigned short* dst; float* nd; int r;
  if (row < BB * LL) { src = Q; dst = Qb; nd = qn; r = row; }
  else { src = K; dst = Kb; nd = kn; r = row - BB * LL; }
  const float* p = src + (size_t)r * DD + part * 8;
  f32x4 a = *(const f32x4*)p, b = *(const f32x4*)(p + 4);
  float s = a.x * a.x + a.y * a.y + a.z * a.z + a.w * a.w +
            b.x * b.x + b.y * b.y + b.z * b.z + b.w * b.w;
  s += __shfl_xor(s, 1); s += __shfl_xor(s, 2);
  s += __shfl_xor(s, 4); s += __shfl_xor(s, 8);
  u16x8 h;
  h[0] = f2bf(a.x); h[1] = f2bf(a.y); h[2] = f2bf(a.z); h[3] = f2bf(a.w);
  h[4] = f2bf(b.x); h[5] = f2bf(b.y); h[6] = f2bf(b.z); h[7] = f2bf(b.w);
  *(u16x8*)(dst + (size_t)r * DD + part * 8) = h;
  if (part == 0) nd[r] = s;
}

// ---- V transpose to bf16: VT[b][d][k] = bf16(V[b][k][d]) ----
__global__ __launch_bounds__(256) void kVT(const float* __restrict__ V,
                                           unsigned short* __restrict__ VT) {
  __shared__ unsigned short t[128][68];
  int bx = blockIdx.x;
  int kt = bx & 63, b = bx >> 6;
  int k0 = kt * 64;
  int tid = threadIdx.x;
  const float* Vb = V + ((size_t)b * LL + k0) * DD;
  #pragma unroll
  for (int i = 0; i < 8; ++i) {
    int flat = tid + i * 256;
    int row = flat >> 5, c4 = flat & 31;
    f32x4 v = *(const f32x4*)(Vb + row * DD + c4 * 4);
    #pragma unroll
    for (int j = 0; j < 4; ++j) t[c4 * 4 + j][row] = f2bf(v[j]);
  }
  __syncthreads();
  unsigned short* Ob = VT + (size_t)b * DD * LL + k0;
  #pragma unroll
  for (int i = 0; i < 8; ++i) {
    int flat = tid + i * 256;
    int d = flat >> 4, c = flat & 15;
    *(u16x4*)(Ob + (size_t)d * LL + c * 4) = *(const u16x4*)&t[d][c * 4];
  }
}

// ---- kernel A4: dist2 + scores + row-sum-exp (unchanged from round 4) ----
__global__ __launch_bounds__(256, 2) void kA4(
    const unsigned short* __restrict__ Qb, const unsigned short* __restrict__ Kb,
    const int* __restrict__ mask, const float* __restrict__ qn,
    const float* __restrict__ kn, float* __restrict__ scores,
    float* __restrict__ dist2, float* __restrict__ l_part) {
  __shared__ float slds[4][16][64];  // [wave][q][k-chunk], XOR-swizzled in k
  int bx = blockIdx.x;
  int qb = bx & 63, b = (bx >> 6) & 3, ks = bx >> 8;
  int tid = threadIdx.x;
  int w = tid >> 6, lane = tid & 63, lr = lane >> 4, lc = lane & 15;
  int qg = qb * 64 + w * 16;
  size_t bL = (size_t)b * LL;

  bf16x8 qf[4];
  {
    const unsigned short* qp = Qb + (bL + qg + lc) * DD;
    #pragma unroll
    for (int c = 0; c < 4; ++c)
      qf[c] = *(const bf16x8*)(qp + c * 32 + lr * 8);
  }

  float qn_s[4];
  size_t rowoff[4];
  #pragma unroll
  for (int s = 0; s < 4; ++s) {
    qn_s[s] = qn[bL + qg + s * 4 + lr];
    rowoff[s] = (bL + qg + s * 4 + lr) * (size_t)LL;
  }
  float l_acc[4] = {0.f, 0.f, 0.f, 0.f};

  auto MFMA_PHASE = [&](int t) {
    int k0 = ks * 1024 + t * 64;
    #pragma unroll
    for (int m = 0; m < 4; ++m) {
      const unsigned short* kp = Kb + (bL + k0 + m * 16 + lc) * DD;
      f32x4 S = (f32x4){0.f, 0.f, 0.f, 0.f};
      #pragma unroll
      for (int c = 0; c < 4; ++c) {
        bf16x8 af = *(const bf16x8*)(kp + c * 32 + lr * 8);
        S = __builtin_amdgcn_mfma_f32_16x16x32_bf16(af, qf[c], S, 0, 0, 0);
      }
      int swz = ((m * 4 + lr) ^ lc) & 15;
      *(f32x4*)&slds[w][lc][swz * 4] = S;
    }
  };

  auto LOADM = [&](i32x4 (&mr)[4], int t) {
    int k0 = ks * 1024 + t * 64;
    #pragma unroll
    for (int s = 0; s < 4; ++s)
      mr[s] = *(const i32x4*)(mask + rowoff[s] + k0 + lc * 4);
  };

  auto STORE_PHASE = [&](i32x4 (&mr)[4], int t) {
    int k0 = ks * 1024 + t * 64;
    f32x4 kn4 = *(const f32x4*)(kn + bL + k0 + lc * 4);
    #pragma unroll
    for (int s = 0; s < 4; ++s) {
      int row = s * 4 + lr;
      int swz = (lc ^ row) & 15;
      f32x4 S = *(const f32x4*)&slds[w][row][swz * 4];
      f32x4 d2, sv;
      float le = 0.f;
      #pragma unroll
      for (int r = 0; r < 4; ++r) {
        float d = qn_s[s] + kn4[r] - 2.0f * S[r];
        d2[r] = d;
        float sc = d * (-1.0f / 256.0f);
        bool ms = (mr[s][r] == 0);
        sv[r] = ms ? -__builtin_inff() : sc;
        le += ms ? 0.f : __expf(sc);
      }
      size_t off = rowoff[s] + k0 + lc * 4;
      *(f32x4*)(dist2 + off) = d2;
      *(f32x4*)(scores + off) = sv;
      le += __shfl_xor(le, 1); le += __shfl_xor(le, 2);
      le += __shfl_xor(le, 4); le += __shfl_xor(le, 8);
      l_acc[s] += le;
    }
  };

  i32x4 mA[4], mB[4];
  LOADM(mA, 0);
  #pragma unroll
  for (int tt = 0; tt < 8; ++tt) {
    MFMA_PHASE(2 * tt);
    LOADM(mB, 2 * tt + 1);
    STORE_PHASE(mA, 2 * tt);
    MFMA_PHASE(2 * tt + 1);
    LOADM(mA, (tt < 7) ? (2 * tt + 2) : 0);
    STORE_PHASE(mB, 2 * tt + 1);
  }

  if (lc == 0) {
    #pragma unroll
    for (int s = 0; s < 4; ++s)
      l_part[(size_t)ks * (BB * LL) + bL + qg + s * 4 + lr] = l_acc[s];
  }
}

// ---- kernel B5: double-buffered, reg-prefetched, 1 barrier/iter ----
// grid 1024: qb(64) x b(4) x ks(4); block 256 (4 waves), k-range 1024/block.
// Per iter: MFMA on buf[cur] while next tile's scores/V (loaded to regs one
// iter ahead) are exp'd, stored to attn, and ds_written to buf[nxt]; loads
// for t+2 issued before the single barrier.
__global__ __launch_bounds__(256, 2) void kB5(
    const float* __restrict__ scores, const float* __restrict__ l_part,
    const unsigned short* __restrict__ VT, float* __restrict__ attn,
    float* __restrict__ O_part) {
  __shared__ short p_lds[2][64][72];
  __shared__ short v_lds[2][128][72];
  __shared__ float rl_lds[64];
  int bx = blockIdx.x;
  int qb = bx & 63, b = (bx >> 6) & 3, ks = bx >> 8;
  int tid = threadIdx.x;
  int wq = tid >> 6, l = tid & 63, lr = l >> 4, lc = l & 15;
  int q0 = qb * 64;
  int k_base = ks * 1024;

  if (tid < 64) {
    float s = 0.f;
    #pragma unroll
    for (int sp = 0; sp < 4; ++sp)
      s += l_part[(size_t)sp * (BB * LL) + (size_t)b * LL + q0 + tid];
    rl_lds[tid] = 1.0f / s;
  }

  const float* Sb = scores + (size_t)b * LL * LL + (size_t)q0 * LL;
  float* Ab = attn + (size_t)b * LL * LL + (size_t)q0 * LL;
  const unsigned short* Vb = VT + (size_t)b * DD * LL;

  // per-lane staging identities
  int srow[4], sc4[4];   // scores/attn: 4 chunks, 16 rows x 16 segs
  #pragma unroll
  for (int i = 0; i < 4; ++i) {
    int flat = tid + i * 256;
    srow[i] = flat >> 4; sc4[i] = flat & 15;
  }
  int vd[8], vc[8];      // V: 8 chunks, 128 rows x 16 segs
  #pragma unroll
  for (int i = 0; i < 8; ++i) {
    int flat = tid + i * 256;
    vd[i] = flat >> 4; vc[i] = flat & 15;
  }

  f32x4 rS[4];
  u16x4 rV[8];
  auto LOADT = [&](int t) {
    int k0 = k_base + t * 64;
    #pragma unroll
    for (int i = 0; i < 4; ++i)
      rS[i] = __builtin_nontemporal_load(
          (const f32x4*)(Sb + (size_t)srow[i] * LL + k0 + sc4[i] * 4));
    #pragma unroll
    for (int i = 0; i < 8; ++i)
      rV[i] = *(const u16x4*)(Vb + (size_t)vd[i] * LL + k0 + vc[i] * 4);
  };

  auto PROCESS = [&](int t, int buf) {  // consume rS/rV -> attn + lds[buf]
    int k0 = k_base + t * 64;
    #pragma unroll
    for (int i = 0; i < 4; ++i) {
      float r = rl_lds[srow[i]];
      f32x4 s4 = rS[i];
      f32x4 p4;
      p4.x = __expf(s4.x) * r; p4.y = __expf(s4.y) * r;
      p4.z = __expf(s4.z) * r; p4.w = __expf(s4.w) * r;
      *(f32x4*)(Ab + (size_t)srow[i] * LL + k0 + sc4[i] * 4) = p4;
      u16x4 h;
      h[0] = f2bf(p4.x); h[1] = f2bf(p4.y); h[2] = f2bf(p4.z); h[3] = f2bf(p4.w);
      *(u16x4*)&p_lds[buf][srow[i]][sc4[i] * 4] = h;
    }
    #pragma unroll
    for (int i = 0; i < 8; ++i)
      *(u16x4*)&v_lds[buf][vd[i]][vc[i] * 4] = rV[i];
  };

  f32x4 o[8];
  #pragma unroll
  for (int f = 0; f < 8; ++f) o[f] = (f32x4){0.f, 0.f, 0.f, 0.f};

  // prologue: tile 0 into buf 0; issue tile-1 loads; one barrier
  LOADT(0);
  __syncthreads();          // rl_lds ready
  PROCESS(0, 0);
  LOADT(1);
  __syncthreads();          // buf0 ready

  for (int t = 0; t < 16; ++t) {
    int cur = t & 1;
    // MFMA on buf[cur]
    bf16x8 pa[2];
    #pragma unroll
    for (int c = 0; c < 2; ++c)
      pa[c] = *(bf16x8*)&p_lds[cur][wq * 16 + lc][c * 32 + lr * 8];
    #pragma unroll
    for (int f = 0; f < 8; ++f) {
      #pragma unroll
      for (int c = 0; c < 2; ++c) {
        bf16x8 vb = *(bf16x8*)&v_lds[cur][f * 16 + lc][c * 32 + lr * 8];
        o[f] = __builtin_amdgcn_mfma_f32_16x16x32_bf16(pa[c], vb, o[f], 0, 0, 0);
      }
    }
    if (t < 15) {
      PROCESS(t + 1, cur ^ 1);   // regs loaded last iter -> attn + buf[nxt]
      if (t < 14) LOADT(t + 2);  // issue next loads before the barrier
    }
    __syncthreads();
  }

  float* Ob = O_part + (size_t)ks * ((size_t)BB * LL * DD);
  #pragma unroll
  for (int f = 0; f < 8; ++f) {
    #pragma unroll
    for (int r = 0; r < 4; ++r) {
      int row = q0 + wq * 16 + lr * 4 + r;
      Ob[((size_t)b * LL + row) * DD + f * 16 + lc] = o[f][r];
    }
  }
}

// ---- reduce the four O partials into out ----
__global__ __launch_bounds__(256) void kR(const float* __restrict__ O_part,
                                          float* __restrict__ out) {
  size_t idx = (size_t)blockIdx.x * 256 + threadIdx.x;
  const size_t N4 = (size_t)BB * LL * DD / 4;
  const f32x4* a = (const f32x4*)O_part;
  f32x4 v = (a[idx] + a[idx + N4]) + (a[idx + 2 * N4] + a[idx + 3 * N4]);
  ((f32x4*)out)[idx] = v;
}

extern "C" void kernel_launch(void* const* d_in, const int* in_sizes, int n_in,
                              void* d_out, int out_size, void* d_ws, size_t ws_size,
                              hipStream_t stream) {
  const float* Q = (const float*)d_in[0];
  const float* K = (const float*)d_in[1];
  const float* V = (const float*)d_in[2];
  const int* mask = (const int*)d_in[3];

  float* out = (float*)d_out;                        // [4,4096,128]
  float* attn = out + (size_t)BB * LL * DD;          // [4,4096,4096]
  float* scores = attn + (size_t)BB * LL * LL;       // [4,4096,4096]
  float* dist2 = scores + (size_t)BB * LL * LL;      // [4,4096,4096]

  float* qn = (float*)d_ws;                                   // 16384 f
  float* kn = qn + BB * LL;                                   // 16384 f
  float* l_part = kn + BB * LL;                               // 4*16384 f
  unsigned short* Qbf = (unsigned short*)(l_part + 4 * BB * LL);   // 4 MB
  unsigned short* Kbf = Qbf + (size_t)BB * LL * DD;                // 4 MB
  unsigned short* VTb = Kbf + (size_t)BB * LL * DD;                // 4 MB
  float* O_part = (float*)(VTb + (size_t)BB * LL * DD);            // 4 x 8 MB

  hipLaunchKernelGGL(kNC, dim3(2048), dim3(256), 0, stream, Q, K, Qbf, Kbf, qn, kn);
  hipLaunchKernelGGL(kVT, dim3(256), dim3(256), 0, stream, V, VTb);
  hipLaunchKernelGGL(kA4, dim3(1024), dim3(256), 0, stream, Qbf, Kbf, mask, qn,
                     kn, scores, dist2, l_part);
  hipLaunchKernelGGL(kB5, dim3(1024), dim3(256), 0, stream, scores, l_part, VTb,
                     attn, O_part);
  hipLaunchKernelGGL(kR, dim3(2048), dim3(256), 0, stream, O_part, out);
}